// Round 1
// baseline (4786.869 us; speedup 1.0000x reference)
//
#include <hip/hip_runtime.h>
#include <cstddef>
#include <cstdint>

// ---------------------------------------------------------------------------
// LSTM layer: T=512, B=64, I=512, H=512.
// Phase 1: xW = x @ W + b  (bf16 MFMA GEMM, M=32768, K=512, N=2048)
// Phase 2: persistent recurrent kernel, 32 WGs, U-slices register-resident,
//          1 device-scope grid barrier per step, ping-pong bf16 a-exchange.
// ---------------------------------------------------------------------------

#define T_STEPS 512
#define NB      64      // batch
#define HID     512
#define G4      2048    // 4*H
#define MROWS   (T_STEPS * NB)   // 32768
#define KDIM    512
#define NWG     32      // recurrent workgroups; each owns 16 hidden units

typedef short bf16x8 __attribute__((ext_vector_type(8)));
typedef float f32x4  __attribute__((ext_vector_type(4)));

__device__ __forceinline__ float bf2f(unsigned short s) {
    unsigned u = ((unsigned)s) << 16;
    float f; __builtin_memcpy(&f, &u, 4); return f;
}
__device__ __forceinline__ unsigned short f2bf(float f) {
    unsigned u; __builtin_memcpy(&u, &f, 4);
    u = (u + 0x7FFFu + ((u >> 16) & 1u)) >> 16;
    return (unsigned short)u;
}

// ---------------- kernel 1: cast x to bf16 (also zero the barrier vars) ----
__global__ void cast_x_kernel(const float* __restrict__ x,
                              unsigned short* __restrict__ o,
                              unsigned* __restrict__ bar) {
    if (blockIdx.x == 0 && threadIdx.x == 0) { bar[0] = 0u; bar[1] = 0u; }
    size_t i = (size_t)blockIdx.x * blockDim.x + threadIdx.x;  // one float4 each
    float4 v = ((const float4*)x)[i];
    ushort4 r;
    r.x = f2bf(v.x); r.y = f2bf(v.y); r.z = f2bf(v.z); r.w = f2bf(v.w);
    ((ushort4*)o)[i] = r;
}

// ---------------- kernel 2: transpose+cast [512][2048] f32 -> [2048][512] bf16
__global__ void transpose_cast(const float* __restrict__ src,
                               unsigned short* __restrict__ dst) {
    __shared__ float tile[64][65];
    const int n0 = blockIdx.x * 64;   // 32 tiles
    const int k0 = blockIdx.y * 64;   // 8 tiles
    const int c  = threadIdx.x & 63;
    const int r0 = threadIdx.x >> 6;  // 0..3
    for (int p = 0; p < 16; ++p) {
        int r = p * 4 + r0;           // k-local
        tile[r][c] = src[(size_t)(k0 + r) * G4 + n0 + c];
    }
    __syncthreads();
    for (int p = 0; p < 16; ++p) {
        int r = p * 4 + r0;           // n-local
        dst[(size_t)(n0 + r) * KDIM + k0 + c] = f2bf(tile[c][r]);
    }
}

// ---------------- kernel 3: bf16 MFMA GEMM: C[M][2048] = A[M][512]*Bt^T + bias
// A: [M][K] bf16 row-major; Bt: [N][K] bf16 (pre-transposed); both K-contig.
__global__ __launch_bounds__(256) void gemm_xw(
        const unsigned short* __restrict__ A,
        const unsigned short* __restrict__ Bt,
        const float* __restrict__ bias,
        unsigned short* __restrict__ C) {
    // LDS tiles padded to 56 (=112B rows: 16B-aligned, ~2-way banks = free)
    __shared__ unsigned short As[128][56];
    __shared__ unsigned short Bs[128][56];
    const int m0 = blockIdx.x * 128;
    const int n0 = blockIdx.y * 128;
    const int tid = threadIdx.x;
    const int lane = tid & 63, wave = tid >> 6;
    const int quad = lane >> 4, l16 = lane & 15;
    const int wm = (wave >> 1) * 64, wn = (wave & 1) * 64;
    f32x4 acc[4][4];
    for (int i = 0; i < 4; ++i)
        for (int j = 0; j < 4; ++j) acc[i][j] = (f32x4)0.0f;
    const int srow = tid >> 2, scol = (tid & 3) * 8;
    for (int k0 = 0; k0 < KDIM; k0 += 32) {
        __syncthreads();
        for (int p = 0; p < 2; ++p) {
            int row = p * 64 + srow;
            *(uint4*)&As[row][scol] =
                *(const uint4*)&A[(size_t)(m0 + row) * KDIM + k0 + scol];
            *(uint4*)&Bs[row][scol] =
                *(const uint4*)&Bt[(size_t)(n0 + row) * KDIM + k0 + scol];
        }
        __syncthreads();
        bf16x8 af[4], bf[4];
        for (int i = 0; i < 4; ++i)
            af[i] = *(const bf16x8*)&As[wm + i * 16 + l16][quad * 8];
        for (int j = 0; j < 4; ++j)
            bf[j] = *(const bf16x8*)&Bs[wn + j * 16 + l16][quad * 8];
        for (int i = 0; i < 4; ++i)
            for (int j = 0; j < 4; ++j)
                acc[i][j] = __builtin_amdgcn_mfma_f32_16x16x32_bf16(
                    af[i], bf[j], acc[i][j], 0, 0, 0);
    }
    for (int i = 0; i < 4; ++i)
        for (int j = 0; j < 4; ++j) {
            int col = n0 + wn + j * 16 + l16;
            float bv = bias[col];
            for (int r = 0; r < 4; ++r) {
                int row = m0 + wm + i * 16 + quad * 4 + r;
                C[(size_t)row * G4 + col] = f2bf(acc[i][j][r] + bv);
            }
        }
}

// ---------------- device-scope grid barrier (blocks co-resident: 32 << 256 CUs)
__device__ __forceinline__ void gridbar(unsigned* bar, unsigned nblk) {
    __syncthreads();
    if (threadIdx.x == 0) {
        unsigned g = __hip_atomic_load(&bar[1], __ATOMIC_RELAXED,
                                       __HIP_MEMORY_SCOPE_AGENT);
        __threadfence();  // release my block's prior global writes
        unsigned old = __hip_atomic_fetch_add(&bar[0], 1u, __ATOMIC_ACQ_REL,
                                              __HIP_MEMORY_SCOPE_AGENT);
        if (old == nblk - 1) {
            __hip_atomic_store(&bar[0], 0u, __ATOMIC_RELAXED,
                               __HIP_MEMORY_SCOPE_AGENT);
            __hip_atomic_fetch_add(&bar[1], 1u, __ATOMIC_RELEASE,
                                   __HIP_MEMORY_SCOPE_AGENT);
        } else {
            while (__hip_atomic_load(&bar[1], __ATOMIC_ACQUIRE,
                                     __HIP_MEMORY_SCOPE_AGENT) == g) {
                __builtin_amdgcn_s_sleep(1);
            }
        }
        __threadfence();  // acquire: invalidate stale L2 before plain reads
    }
    __syncthreads();
}

// ---------------- kernel 4: persistent recurrence -------------------------
// WG g owns hidden units [g*16, g*16+16). Wave w = gate w (u,f,o,c).
// B-fragments (Ut rows w*512+j0+l16, full K) live in registers: bq[16].
__global__ __launch_bounds__(256) void lstm_rec(
        const unsigned short* __restrict__ xW,   // [M][2048] bf16
        const unsigned short* __restrict__ Ut,   // [2048][512] bf16
        const float* __restrict__ a0,            // [64][512] f32
        float* __restrict__ out,                 // [T*64][512] f32
        unsigned short* __restrict__ abuf,       // [2][64][512] bf16
        unsigned* __restrict__ bar) {
    __shared__ unsigned short a_lds[64][264];    // half-K staging (pad: 528B rows)
    __shared__ float gbuf[4][64][17];            // gate exchange
    const int g   = blockIdx.x;
    const int tid = threadIdx.x;
    const int wave = tid >> 6;                   // gate index
    const int lane = tid & 63;
    const int quad = lane >> 4, l16 = lane & 15;
    const int j0 = g * 16;

    // --- load register-resident B fragments (once; reused 512 steps) ---
    bf16x8 bq[16];
    {
        const unsigned short* urow =
            Ut + (size_t)(wave * HID + j0 + l16) * KDIM + quad * 8;
        for (int s = 0; s < 16; ++s)
            bq[s] = *(const bf16x8*)(urow + s * 32);
    }
    // --- per-thread cell state: thread owns (b_own, jj0..jj0+3) ---
    const int b_own = tid >> 2;
    const int jj0   = (tid & 3) * 4;
    float aown[4];
    {
        const float4 v = *(const float4*)&a0[(size_t)b_own * HID + j0 + jj0];
        aown[0] = v.x; aown[1] = v.y; aown[2] = v.z; aown[3] = v.w;
        union { uint2 v2; unsigned short s[4]; } pk;
        for (int i = 0; i < 4; ++i) pk.s[i] = f2bf(aown[i]);
        *(uint2*)&abuf[(size_t)b_own * HID + j0 + jj0] = pk.v2;  // buf 0
    }
    gridbar(bar, gridDim.x);

    for (int t = 0; t < T_STEPS; ++t) {
        const unsigned short* acur = abuf + (size_t)(t & 1) * (NB * HID);
        unsigned short* anxt = abuf + (size_t)((t + 1) & 1) * (NB * HID);
        f32x4 acc[4];
        for (int mt = 0; mt < 4; ++mt) acc[mt] = (f32x4)0.0f;
        for (int h = 0; h < 2; ++h) {            // K in two 256-halves
            if (h) __syncthreads();
            {   // stage a_{t-1} half into LDS (thread: row tid>>2, 128B seg)
                const int r = tid >> 2, seg = tid & 3;
                const uint4* src =
                    (const uint4*)(acur + (size_t)r * HID + h * 256 + seg * 64);
                uint4* dst = (uint4*)&a_lds[r][seg * 64];
                for (int i = 0; i < 8; ++i) dst[i] = src[i];
            }
            __syncthreads();
            for (int mt = 0; mt < 4; ++mt)
                for (int s = 0; s < 8; ++s) {
                    bf16x8 af = *(const bf16x8*)
                        &a_lds[mt * 16 + l16][s * 32 + quad * 8];
                    acc[mt] = __builtin_amdgcn_mfma_f32_16x16x32_bf16(
                        af, bq[h * 8 + s], acc[mt], 0, 0, 0);
                }
        }
        // D layout: row = quad*4+reg (batch), col = l16 (unit)
        for (int mt = 0; mt < 4; ++mt)
            for (int r = 0; r < 4; ++r)
                gbuf[wave][mt * 16 + quad * 4 + r][l16] = acc[mt][r];
        __syncthreads();
        // --- gate stage (per-thread 4 units, fp32 state in regs) ---
        {
            const size_t m = (size_t)t * NB + b_own;
            const unsigned short* xp = xW + m * G4 + j0 + jj0;
            float xg[4][4];
            for (int w = 0; w < 4; ++w) {
                union { uint2 v2; unsigned short s[4]; } u;
                u.v2 = *(const uint2*)(xp + (size_t)w * HID);
                for (int i = 0; i < 4; ++i) xg[w][i] = bf2f(u.s[i]);
            }
            float4 ov;
            float* ovp = &ov.x;
            union { uint2 v2; unsigned short s[4]; } pk;
            for (int i = 0; i < 4; ++i) {
                float gu = gbuf[0][b_own][jj0 + i] + xg[0][i];
                float gf = gbuf[1][b_own][jj0 + i] + xg[1][i];
                float go = gbuf[2][b_own][jj0 + i] + xg[2][i];
                float gc = gbuf[3][b_own][jj0 + i] + xg[3][i];
                float su = 1.f / (1.f + __expf(-gu));
                float sf = 1.f / (1.f + __expf(-gf));
                float so = 1.f / (1.f + __expf(-go));
                float e2 = __expf(2.f * gc);
                float tc = 1.f - 2.f / (e2 + 1.f);          // tanh(gc)
                float cc = su * tc + sf * aown[i];           // forget * a_{t-1}
                float ec = __expf(2.f * cc);
                float th = 1.f - 2.f / (ec + 1.f);           // tanh(c)
                float a  = so * th;
                aown[i] = a;
                ovp[i]  = a;
                pk.s[i] = f2bf(a);
            }
            *(float4*)&out[m * HID + j0 + jj0] = ov;
            *(uint2*)&anxt[(size_t)b_own * HID + j0 + jj0] = pk.v2;
        }
        gridbar(bar, gridDim.x);   // one barrier per step (ping-pong safe)
    }
}

// ---------------------------------------------------------------------------
extern "C" void kernel_launch(void* const* d_in, const int* in_sizes, int n_in,
                              void* d_out, int out_size, void* d_ws, size_t ws_size,
                              hipStream_t stream) {
    (void)in_sizes; (void)n_in; (void)out_size; (void)ws_size;
    const float* x    = (const float*)d_in[0];   // [T,B,I]
    const float* a0   = (const float*)d_in[1];   // [B,H]
    const float* W    = (const float*)d_in[2];   // [I,4H]
    const float* U    = (const float*)d_in[3];   // [H,4H]
    const float* bias = (const float*)d_in[4];   // [4H]
    float* out = (float*)d_out;

    char* ws = (char*)d_ws;
    unsigned short* xbf  = (unsigned short*)(ws);                 // 33,554,432 B
    unsigned short* Wt   = (unsigned short*)(ws + 33554432);      //  2,097,152 B
    unsigned short* Ut   = (unsigned short*)(ws + 35651584);      //  2,097,152 B
    unsigned short* xWp  = (unsigned short*)(ws + 37748736);      // 134,217,728 B
    unsigned short* abuf = (unsigned short*)(ws + 171966464);     //    131,072 B
    unsigned*       bar  = (unsigned*)(ws + 172097536);           //          8 B

    cast_x_kernel<<<16384, 256, 0, stream>>>(x, xbf, bar);
    transpose_cast<<<dim3(32, 8), 256, 0, stream>>>(W, Wt);
    transpose_cast<<<dim3(32, 8), 256, 0, stream>>>(U, Ut);
    gemm_xw<<<dim3(256, 16), 256, 0, stream>>>(xbf, Wt, bias, xWp);
    lstm_rec<<<NWG, 256, 0, stream>>>(xWp, Ut, a0, out, abuf, bar);
}